// Round 3
// baseline (548.897 us; speedup 1.0000x reference)
//
#include <hip/hip_runtime.h>

// DTCWT level=3 on (8,512,512,3) f32 -> (8,1024,1024,3) f32.
// Three fused kernels (one per level). Stage A row-filters (along H) with
// float4 global loads, register-transposes into an XOR-swizzled LDS tile.
// Stage B col-filters (along W) via b128 LDS reads, combines the dual trees
// in registers, 12 B/thread contiguous stores per band.
// For LVL>=1, stage B is z-PAIR split: the dual-tree combine couples only
// z-pairs {0,3} and {1,2}; each pair is self-contained given the LDS data,
// so threads 0-127 handle pair {0,3} and 128-255 handle {1,2} -> all 256
// threads active (was 128), per-thread chain halved.
// __launch_bounds__(256,5): VGPR<=102 -> 5 blocks/CU (LDS 31232*5 fits 160K).
// afb: out[i] = sum_t f[t] * x[(2i+5-t) mod N]
// Tile(m,n) at rows [m*512,+512), cols [n*512,+512) of out; tile-local:
// lowpass 64x64 at (0,0); level-j bands (H=256,128,64): LH (0,H), HL (H,0), HH (H,H).

#define FF 0.08838834764832f
#define GG 0.01122679215254f
#define HHc 0.69587998903400f
#define AAc 0.03516384f
#define BBc 0.08832942f
#define CCc 0.23389032f
#define DDc 0.76027237f
#define EEc 0.58751830f
#define KKc 0.11430184f

// [bank: 0=Faf, 1=af][tree m][lo/hi][tap]
__device__ __constant__ float c_filt[2][2][2][10] = {
  { // Faf (first stage)
    { {0.f,-FF, FF, HHc, HHc, FF,-FF, GG, GG, 0.f},
      {0.f,-GG, GG, FF, FF,-HHc, HHc,-FF,-FF, 0.f} },
    { {GG, GG,-FF, FF, HHc, HHc, FF,-FF, 0.f, 0.f},
      {0.f, 0.f,-FF,-FF, HHc,-HHc, FF, FF, GG,-GG} }
  },
  { // af (q-shift, levels >= 1)
    { {AAc, 0.f,-BBc, CCc, DDc, EEc, 0.f,-KKc, 0.f, 0.f},
      {0.f, 0.f,-KKc, 0.f, EEc,-DDc, CCc, BBc, 0.f,-AAc} },
    { {0.f, 0.f,-KKc, 0.f, EEc, DDc, CCc,-BBc, 0.f, AAc},
      {-AAc, 0.f, BBc, CCc,-DDc, EEc, 0.f,-KKc, 0.f, 0.f} }
  }
};

__device__ __forceinline__ void cmb(float& a, float& b) {
  const float k = 0.70710678118654752440f;
  const float s = (a + b) * k, d = (a - b) * k;
  a = s; b = d;
}

// Injective bank swizzle on float4 indices: permutes low 3 bits (bank group)
// as a function of bits >=3. Range-preserving within 8-aligned octets.
__device__ __forceinline__ int swz4(int f4) { return f4 ^ ((f4 >> 3) & 7); }

template<int LVL, int N, int Ho, int Wo>
__global__ __launch_bounds__(256, 5) void fused_level(
    const float* __restrict__ src,
    float* __restrict__ llout,
    float* __restrict__ out)
{
  constexpr int half = N / 2;
  constexpr int W2 = 2 * Wo + 8;               // col halo span
  constexpr int NF = (LVL == 0) ? 4 : 8;       // row-filter outputs per position
  constexpr int ROWF = 3 * N;                  // floats per image row
  constexpr int FL = 3 * W2;                   // flat floats per LDS row
  constexpr int SIF4 = (3 * W2 * NF) / 4 + 4;  // il-stride in float4 units
  constexpr size_t ZS = (size_t)8 * N * N * 3;
  constexpr size_t ZOUT = (size_t)8 * half * half * 3;
  static_assert(LVL == 0 ? (Ho * Wo == 256) : (Ho * Wo * 2 == 256), "thread map");
  __shared__ __align__(16) float inter[Ho * SIF4 * 4];

  const int jt = blockIdx.x, it = blockIdx.y, b = blockIdx.z;
  const int i0 = it * Ho, j0 = jt * Wo;
  const int tid = threadIdx.x;

  int base = (2 * j0 - 4) * 3;                 // multiple of 4 floats (16B)
  if (base < 0) base += ROWF;

  // ---- Stage A: row filter along H, float4 global loads -> swizzled LDS ----
  constexpr int I4 = FL / 4;
  for (int item = tid; item < Ho * I4; item += 256) {
    const int il = item / I4;
    const int q4 = (item - il * I4) * 4;       // flat local (w*3+c), mult of 4
    int fg = base + q4;
    if (fg >= ROWF) fg -= ROWF;                // never straddles a float4
    const int ig = i0 + il;
    float acc[NF][4];
#pragma unroll
    for (int f = 0; f < NF; ++f)
#pragma unroll
      for (int k = 0; k < 4; ++k) acc[f][k] = 0.f;

    if constexpr (LVL == 0) {
      const float* sp = src + (size_t)b * N * ROWF + fg;
#pragma unroll
      for (int t = 0; t < 10; ++t) {
        const int r = (2 * ig + 5 - t) & (N - 1);
        const float4 v = *(const float4*)(sp + (size_t)r * ROWF);
#pragma unroll
        for (int f = 0; f < 4; ++f) {
          const float fc = c_filt[0][f >> 1][f & 1][t];
          acc[f][0] += fc * v.x; acc[f][1] += fc * v.y;
          acc[f][2] += fc * v.z; acc[f][3] += fc * v.w;
        }
      }
#pragma unroll
      for (int f = 0; f < 4; ++f)
#pragma unroll
        for (int k = 0; k < 4; ++k) acc[f][k] *= 0.5f;  // x/2 folded
    } else {
#pragma unroll
      for (int z = 0; z < 4; ++z) {
        const int m = z >> 1;
        const float* sp = src + (size_t)z * ZS + (size_t)b * N * ROWF + fg;
#pragma unroll
        for (int t = 0; t < 10; ++t) {
          const int r = (2 * ig + 5 - t) & (N - 1);
          const float4 v = *(const float4*)(sp + (size_t)r * ROWF);
          const float fl = c_filt[1][m][0][t], fh = c_filt[1][m][1][t];
          acc[2 * z][0] += fl * v.x; acc[2 * z][1] += fl * v.y;
          acc[2 * z][2] += fl * v.z; acc[2 * z][3] += fl * v.w;
          acc[2 * z + 1][0] += fh * v.x; acc[2 * z + 1][1] += fh * v.y;
          acc[2 * z + 1][2] += fh * v.z; acc[2 * z + 1][3] += fh * v.w;
        }
      }
    }
    // transpose-write: per flat position fq, NF filters contiguous as float4s.
    // NF=4: float4 index = fq. NF=8: float4 indices = 2*fq, 2*fq+1.
#pragma unroll
    for (int k = 0; k < 4; ++k) {
      const int fq = q4 + k;
      if constexpr (NF == 4) {
        float4 w = make_float4(acc[0][k], acc[1][k], acc[2][k], acc[3][k]);
        *(float4*)&inter[(il * SIF4 + swz4(fq)) * 4] = w;
      } else {
        float4 w0 = make_float4(acc[0][k], acc[1][k], acc[2][k], acc[3][k]);
        float4 w1 = make_float4(acc[4][k], acc[5][k], acc[6][k], acc[7][k]);
        *(float4*)&inter[(il * SIF4 + swz4(2 * fq)) * 4] = w0;
        *(float4*)&inter[(il * SIF4 + swz4(2 * fq + 1)) * 4] = w1;
      }
    }
  }
  __syncthreads();

  // ---- Stage B: col filter along W from LDS, combine, contiguous stores ----
  const size_t outB = (size_t)b * (1024u * 1024u * 3u);
  if constexpr (LVL == 0) {
    // 256 threads = Ho x Wo; each computes all 4 z.
    const int il = tid / Wo, jl = tid - (tid / Wo) * Wo;
    float LL[4][3] = {}, LH[4][3] = {}, HL[4][3] = {}, HH[4][3] = {};
#pragma unroll
    for (int s = 0; s < 10; ++s) {
      const int wl = 2 * jl + 9 - s;
#pragma unroll
      for (int c = 0; c < 3; ++c) {
        const int f4 = wl * 3 + c;
        const float4 v = *(const float4*)&inter[(il * SIF4 + swz4(f4)) * 4];
        const float a0 = v.x, d0 = v.y, a1 = v.z, d1 = v.w;
#pragma unroll
        for (int n = 0; n < 2; ++n) {
          const float fl = c_filt[0][n][0][s], fh = c_filt[0][n][1][s];
          LL[n][c] += fl * a0; LH[n][c] += fh * a0;
          HL[n][c] += fl * d0; HH[n][c] += fh * d0;
          LL[2 + n][c] += fl * a1; LH[2 + n][c] += fh * a1;
          HL[2 + n][c] += fl * d1; HH[2 + n][c] += fh * d1;
        }
      }
    }
#pragma unroll
    for (int c = 0; c < 3; ++c) {
      cmb(LH[0][c], LH[3][c]); cmb(LH[1][c], LH[2][c]);
      cmb(HL[0][c], HL[3][c]); cmb(HL[1][c], HL[2][c]);
      cmb(HH[0][c], HH[3][c]); cmb(HH[1][c], HH[2][c]);
    }
    const int ig = i0 + il, jg = j0 + jl;
#pragma unroll
    for (int z = 0; z < 4; ++z) {
      const int m = z >> 1, n = z & 1;
      const int r0 = m * 512, c0 = n * 512;
      float* pLL = llout + (size_t)z * ZOUT + (((size_t)b * half + ig) * half + jg) * 3;
      pLL[0] = LL[z][0]; pLL[1] = LL[z][1]; pLL[2] = LL[z][2];
      float* pLH = out + outB + ((size_t)(r0 + ig) * 1024 + (c0 + half + jg)) * 3;
      pLH[0] = LH[z][0]; pLH[1] = LH[z][1]; pLH[2] = LH[z][2];
      float* pHL = out + outB + ((size_t)(r0 + half + ig) * 1024 + (c0 + jg)) * 3;
      pHL[0] = HL[z][0]; pHL[1] = HL[z][1]; pHL[2] = HL[z][2];
      float* pHH = out + outB + ((size_t)(r0 + half + ig) * 1024 + (c0 + half + jg)) * 3;
      pHH[0] = HH[z][0]; pHH[1] = HH[z][1]; pHH[2] = HH[z][2];
    }
  } else {
    // z-PAIR split: pr=0 -> z{0,3}, pr=1 -> z{1,2}. pr is wave-uniform
    // (tid>>7), so no divergence. Each pair's cmb is thread-local.
    const int pr = tid >> 7;
    const int t7 = tid & 127;
    const int il = t7 / Wo, jl = t7 - (t7 / Wo) * Wo;
    const int za = pr, zb = 3 - pr;            // za&1 == pr, zb&1 == 1-pr
    float LLa[3] = {}, LHa[3] = {}, HLa[3] = {}, HHa[3] = {};
    float LLb[3] = {}, LHb[3] = {}, HLb[3] = {}, HHb[3] = {};
#pragma unroll
    for (int s = 0; s < 10; ++s) {
      const int wl = 2 * jl + 9 - s;
      const float fla = c_filt[1][pr][0][s],     fha = c_filt[1][pr][1][s];
      const float flb = c_filt[1][1 - pr][0][s], fhb = c_filt[1][1 - pr][1][s];
#pragma unroll
      for (int c = 0; c < 3; ++c) {
        const int f4 = (wl * 3 + c) * 2;
        // v0 = {z0lo, z0hi, z1lo, z1hi}, v1 = {z2lo, z2hi, z3lo, z3hi}
        const float4 v0 = *(const float4*)&inter[(il * SIF4 + swz4(f4)) * 4];
        const float4 v1 = *(const float4*)&inter[(il * SIF4 + swz4(f4 + 1)) * 4];
        const float aa = pr ? v0.z : v0.x, da = pr ? v0.w : v0.y;  // za in {0,1}
        const float ab = pr ? v1.x : v1.z, db = pr ? v1.y : v1.w;  // zb in {3,2}
        LLa[c] += fla * aa; LHa[c] += fha * aa;
        HLa[c] += fla * da; HHa[c] += fha * da;
        LLb[c] += flb * ab; LHb[c] += fhb * ab;
        HLb[c] += flb * db; HHb[c] += fhb * db;
      }
    }
    // combine: pairs are exactly (za, zb) with za < zb -> matches
    // cmb(w[0],w[3]) / cmb(w[1],w[2]) argument order.
#pragma unroll
    for (int c = 0; c < 3; ++c) {
      cmb(LHa[c], LHb[c]); cmb(HLa[c], HLb[c]); cmb(HHa[c], HHb[c]);
    }
    const int ig = i0 + il, jg = j0 + jl;
    {
      const int m = za >> 1, n = za & 1;
      const int r0 = m * 512, c0 = n * 512;
      float* pLL;
      if constexpr (LVL == 2)
        pLL = out + outB + ((size_t)(r0 + ig) * 1024 + (c0 + jg)) * 3;
      else
        pLL = llout + (size_t)za * ZOUT + (((size_t)b * half + ig) * half + jg) * 3;
      pLL[0] = LLa[0]; pLL[1] = LLa[1]; pLL[2] = LLa[2];
      float* pLH = out + outB + ((size_t)(r0 + ig) * 1024 + (c0 + half + jg)) * 3;
      pLH[0] = LHa[0]; pLH[1] = LHa[1]; pLH[2] = LHa[2];
      float* pHL = out + outB + ((size_t)(r0 + half + ig) * 1024 + (c0 + jg)) * 3;
      pHL[0] = HLa[0]; pHL[1] = HLa[1]; pHL[2] = HLa[2];
      float* pHH = out + outB + ((size_t)(r0 + half + ig) * 1024 + (c0 + half + jg)) * 3;
      pHH[0] = HHa[0]; pHH[1] = HHa[1]; pHH[2] = HHa[2];
    }
    {
      const int m = zb >> 1, n = zb & 1;
      const int r0 = m * 512, c0 = n * 512;
      float* pLL;
      if constexpr (LVL == 2)
        pLL = out + outB + ((size_t)(r0 + ig) * 1024 + (c0 + jg)) * 3;
      else
        pLL = llout + (size_t)zb * ZOUT + (((size_t)b * half + ig) * half + jg) * 3;
      pLL[0] = LLb[0]; pLL[1] = LLb[1]; pLL[2] = LLb[2];
      float* pLH = out + outB + ((size_t)(r0 + ig) * 1024 + (c0 + half + jg)) * 3;
      pLH[0] = LHb[0]; pLH[1] = LHb[1]; pLH[2] = LHb[2];
      float* pHL = out + outB + ((size_t)(r0 + half + ig) * 1024 + (c0 + jg)) * 3;
      pHL[0] = HLb[0]; pHL[1] = HLb[1]; pHL[2] = HLb[2];
      float* pHH = out + outB + ((size_t)(r0 + half + ig) * 1024 + (c0 + half + jg)) * 3;
      pHH[0] = HHb[0]; pHH[1] = HHb[1]; pHH[2] = HHb[2];
    }
  }
}

extern "C" void kernel_launch(void* const* d_in, const int* in_sizes, int n_in,
                              void* d_out, int out_size, void* d_ws, size_t ws_size,
                              hipStream_t stream) {
  (void)in_sizes; (void)n_in; (void)out_size; (void)ws_size;
  const float* x = (const float*)d_in[0];
  float* out = (float*)d_out;
  float* LL1 = (float*)d_ws;        // 4*8*256*256*3 = 6,291,456 floats
  float* LL2 = LL1 + 6291456;       // 4*8*128*128*3 = 1,572,864 floats

  // L0: 512->256. Tile 8x32, LDS 8*220*16 = 28160 B.
  fused_level<0, 512, 8, 32><<<dim3(8, 32, 8), 256, 0, stream>>>(x, LL1, out);
  // L1: 256->128. Tile 8x16, LDS 8*244*16 = 31232 B.
  fused_level<1, 256, 8, 16><<<dim3(8, 16, 8), 256, 0, stream>>>(LL1, LL2, out);
  // L2: 128->64. Tile 8x16.
  fused_level<2, 128, 8, 16><<<dim3(4, 8, 8), 256, 0, stream>>>(LL2, nullptr, out);
}

// Round 4
// 175.293 us; speedup vs baseline: 3.1313x; 3.1313x over previous
//
#include <hip/hip_runtime.h>

// DTCWT level=3 on (8,512,512,3) f32 -> (8,1024,1024,3) f32.
// Three fused kernels (one per level). Stage A row-filters (along H) with
// float4 global loads, register-transposes into an XOR-swizzled LDS tile.
// Stage B col-filters (along W) via b128 LDS reads, combines the dual trees
// in registers, 12 B/thread contiguous stores per band.
// Stage B is z-PAIR split at ALL levels: the dual-tree combine couples only
// z-pairs {0,3} and {1,2}; each pair is self-contained given the LDS data,
// so the lower half of the block handles pair {0,3} and the upper half
// {1,2} -> all threads active, per-thread chain halved (24 accs, not 48).
// Plain __launch_bounds__(NT): round-3 showed forcing waves-per-eu (,5)
// makes the allocator degrade to VGPR=48 + ~640 MB scratch spill traffic.
// afb: out[i] = sum_t f[t] * x[(2i+5-t) mod N]
// Tile(m,n) at rows [m*512,+512), cols [n*512,+512) of out; tile-local:
// lowpass 64x64 at (0,0); level-j bands (H=256,128,64): LH (0,H), HL (H,0), HH (H,H).

#define FF 0.08838834764832f
#define GG 0.01122679215254f
#define HHc 0.69587998903400f
#define AAc 0.03516384f
#define BBc 0.08832942f
#define CCc 0.23389032f
#define DDc 0.76027237f
#define EEc 0.58751830f
#define KKc 0.11430184f

// [bank: 0=Faf, 1=af][tree m][lo/hi][tap]
__device__ __constant__ float c_filt[2][2][2][10] = {
  { // Faf (first stage)
    { {0.f,-FF, FF, HHc, HHc, FF,-FF, GG, GG, 0.f},
      {0.f,-GG, GG, FF, FF,-HHc, HHc,-FF,-FF, 0.f} },
    { {GG, GG,-FF, FF, HHc, HHc, FF,-FF, 0.f, 0.f},
      {0.f, 0.f,-FF,-FF, HHc,-HHc, FF, FF, GG,-GG} }
  },
  { // af (q-shift, levels >= 1)
    { {AAc, 0.f,-BBc, CCc, DDc, EEc, 0.f,-KKc, 0.f, 0.f},
      {0.f, 0.f,-KKc, 0.f, EEc,-DDc, CCc, BBc, 0.f,-AAc} },
    { {0.f, 0.f,-KKc, 0.f, EEc, DDc, CCc,-BBc, 0.f, AAc},
      {-AAc, 0.f, BBc, CCc,-DDc, EEc, 0.f,-KKc, 0.f, 0.f} }
  }
};

__device__ __forceinline__ void cmb(float& a, float& b) {
  const float k = 0.70710678118654752440f;
  const float s = (a + b) * k, d = (a - b) * k;
  a = s; b = d;
}

// Injective bank swizzle on float4 indices: permutes low 3 bits (bank group)
// as a function of bits >=3. Range-preserving within 8-aligned octets.
__device__ __forceinline__ int swz4(int f4) { return f4 ^ ((f4 >> 3) & 7); }

template<int LVL, int N, int Ho, int Wo, int NT>
__global__ __launch_bounds__(NT) void fused_level(
    const float* __restrict__ src,
    float* __restrict__ llout,
    float* __restrict__ out)
{
  constexpr int half = N / 2;
  constexpr int W2 = 2 * Wo + 8;               // col halo span
  constexpr int NF = (LVL == 0) ? 4 : 8;       // row-filter outputs per position
  constexpr int ROWF = 3 * N;                  // floats per image row
  constexpr int FL = 3 * W2;                   // flat floats per LDS row
  constexpr int SIF4 = (3 * W2 * NF) / 4 + 4;  // il-stride in float4 units
  constexpr size_t ZS = (size_t)8 * N * N * 3;
  constexpr size_t ZOUT = (size_t)8 * half * half * 3;
  static_assert(Ho * Wo * 2 == NT, "stage-B thread map (z-pair split)");
  __shared__ __align__(16) float inter[Ho * SIF4 * 4];

  const int jt = blockIdx.x, it = blockIdx.y, b = blockIdx.z;
  const int i0 = it * Ho, j0 = jt * Wo;
  const int tid = threadIdx.x;

  int base = (2 * j0 - 4) * 3;                 // multiple of 4 floats (16B)
  if (base < 0) base += ROWF;

  // ---- Stage A: row filter along H, float4 global loads -> swizzled LDS ----
  constexpr int I4 = FL / 4;
  for (int item = tid; item < Ho * I4; item += NT) {
    const int il = item / I4;
    const int q4 = (item - il * I4) * 4;       // flat local (w*3+c), mult of 4
    int fg = base + q4;
    if (fg >= ROWF) fg -= ROWF;                // never straddles a float4
    const int ig = i0 + il;
    float acc[NF][4];
#pragma unroll
    for (int f = 0; f < NF; ++f)
#pragma unroll
      for (int k = 0; k < 4; ++k) acc[f][k] = 0.f;

    if constexpr (LVL == 0) {
      const float* sp = src + (size_t)b * N * ROWF + fg;
#pragma unroll
      for (int t = 0; t < 10; ++t) {
        const int r = (2 * ig + 5 - t) & (N - 1);
        const float4 v = *(const float4*)(sp + (size_t)r * ROWF);
#pragma unroll
        for (int f = 0; f < 4; ++f) {
          const float fc = c_filt[0][f >> 1][f & 1][t];
          acc[f][0] += fc * v.x; acc[f][1] += fc * v.y;
          acc[f][2] += fc * v.z; acc[f][3] += fc * v.w;
        }
      }
#pragma unroll
      for (int f = 0; f < 4; ++f)
#pragma unroll
        for (int k = 0; k < 4; ++k) acc[f][k] *= 0.5f;  // x/2 folded
    } else {
#pragma unroll
      for (int z = 0; z < 4; ++z) {
        const int m = z >> 1;
        const float* sp = src + (size_t)z * ZS + (size_t)b * N * ROWF + fg;
#pragma unroll
        for (int t = 0; t < 10; ++t) {
          const int r = (2 * ig + 5 - t) & (N - 1);
          const float4 v = *(const float4*)(sp + (size_t)r * ROWF);
          const float fl = c_filt[1][m][0][t], fh = c_filt[1][m][1][t];
          acc[2 * z][0] += fl * v.x; acc[2 * z][1] += fl * v.y;
          acc[2 * z][2] += fl * v.z; acc[2 * z][3] += fl * v.w;
          acc[2 * z + 1][0] += fh * v.x; acc[2 * z + 1][1] += fh * v.y;
          acc[2 * z + 1][2] += fh * v.z; acc[2 * z + 1][3] += fh * v.w;
        }
      }
    }
    // transpose-write: per flat position fq, NF filters contiguous as float4s.
    // NF=4: float4 index = fq. NF=8: float4 indices = 2*fq, 2*fq+1.
#pragma unroll
    for (int k = 0; k < 4; ++k) {
      const int fq = q4 + k;
      if constexpr (NF == 4) {
        float4 w = make_float4(acc[0][k], acc[1][k], acc[2][k], acc[3][k]);
        *(float4*)&inter[(il * SIF4 + swz4(fq)) * 4] = w;
      } else {
        float4 w0 = make_float4(acc[0][k], acc[1][k], acc[2][k], acc[3][k]);
        float4 w1 = make_float4(acc[4][k], acc[5][k], acc[6][k], acc[7][k]);
        *(float4*)&inter[(il * SIF4 + swz4(2 * fq)) * 4] = w0;
        *(float4*)&inter[(il * SIF4 + swz4(2 * fq + 1)) * 4] = w1;
      }
    }
  }
  __syncthreads();

  // ---- Stage B: col filter along W from LDS, combine, contiguous stores ----
  // z-PAIR split: pr=0 -> pair {0,3}, pr=1 -> pair {1,2}. pr is wave-uniform
  // (block halves), so no divergence. Each pair's cmb is thread-local.
  //   za = pr   (uses m=0 row data for LVL0 / z=pr plane for LVL>=1)
  //   zb = 3-pr (uses m=1 row data for LVL0 / z=3-pr plane for LVL>=1)
  {
    const int pr = (tid >= Ho * Wo) ? 1 : 0;
    const int t7 = tid - pr * Ho * Wo;
    const int il = t7 / Wo, jl = t7 - (t7 / Wo) * Wo;
    const int za = pr, zb = 3 - pr;
    float LLa[3] = {}, LHa[3] = {}, HLa[3] = {}, HHa[3] = {};
    float LLb[3] = {}, LHb[3] = {}, HLb[3] = {}, HHb[3] = {};
#pragma unroll
    for (int s = 0; s < 10; ++s) {
      const int wl = 2 * jl + 9 - s;
      constexpr int BK = (LVL == 0) ? 0 : 1;
      const float fla = c_filt[BK][pr][0][s],     fha = c_filt[BK][pr][1][s];
      const float flb = c_filt[BK][1 - pr][0][s], fhb = c_filt[BK][1 - pr][1][s];
#pragma unroll
      for (int c = 0; c < 3; ++c) {
        float aa, da, ab, db;
        if constexpr (LVL == 0) {
          // v = {a0, d0, a1, d1}: za has m=0 (a0,d0), zb has m=1 (a1,d1);
          // col filter index: za -> n=pr, zb -> n=1-pr (handled via fla/flb).
          const int f4 = wl * 3 + c;
          const float4 v = *(const float4*)&inter[(il * SIF4 + swz4(f4)) * 4];
          aa = v.x; da = v.y; ab = v.z; db = v.w;
        } else {
          // v0 = {z0lo, z0hi, z1lo, z1hi}, v1 = {z2lo, z2hi, z3lo, z3hi}
          const int f4 = (wl * 3 + c) * 2;
          const float4 v0 = *(const float4*)&inter[(il * SIF4 + swz4(f4)) * 4];
          const float4 v1 = *(const float4*)&inter[(il * SIF4 + swz4(f4 + 1)) * 4];
          aa = pr ? v0.z : v0.x; da = pr ? v0.w : v0.y;  // za in {0,1}
          ab = pr ? v1.x : v1.z; db = pr ? v1.y : v1.w;  // zb in {3,2}
        }
        LLa[c] += fla * aa; LHa[c] += fha * aa;
        HLa[c] += fla * da; HHa[c] += fha * da;
        LLb[c] += flb * ab; LHb[c] += fhb * ab;
        HLb[c] += flb * db; HHb[c] += fhb * db;
      }
    }
    // combine: pairs are exactly (za, zb) with za < zb -> matches
    // cmb(w[0],w[3]) / cmb(w[1],w[2]) argument order.
#pragma unroll
    for (int c = 0; c < 3; ++c) {
      cmb(LHa[c], LHb[c]); cmb(HLa[c], HLb[c]); cmb(HHa[c], HHb[c]);
    }
    const int ig = i0 + il, jg = j0 + jl;
    const size_t outB = (size_t)b * (1024u * 1024u * 3u);
    {
      const int m = za >> 1, n = za & 1;
      const int r0 = m * 512, c0 = n * 512;
      float* pLL;
      if constexpr (LVL == 2)
        pLL = out + outB + ((size_t)(r0 + ig) * 1024 + (c0 + jg)) * 3;
      else
        pLL = llout + (size_t)za * ZOUT + (((size_t)b * half + ig) * half + jg) * 3;
      pLL[0] = LLa[0]; pLL[1] = LLa[1]; pLL[2] = LLa[2];
      float* pLH = out + outB + ((size_t)(r0 + ig) * 1024 + (c0 + half + jg)) * 3;
      pLH[0] = LHa[0]; pLH[1] = LHa[1]; pLH[2] = LHa[2];
      float* pHL = out + outB + ((size_t)(r0 + half + ig) * 1024 + (c0 + jg)) * 3;
      pHL[0] = HLa[0]; pHL[1] = HLa[1]; pHL[2] = HLa[2];
      float* pHH = out + outB + ((size_t)(r0 + half + ig) * 1024 + (c0 + half + jg)) * 3;
      pHH[0] = HHa[0]; pHH[1] = HHa[1]; pHH[2] = HHa[2];
    }
    {
      const int m = zb >> 1, n = zb & 1;
      const int r0 = m * 512, c0 = n * 512;
      float* pLL;
      if constexpr (LVL == 2)
        pLL = out + outB + ((size_t)(r0 + ig) * 1024 + (c0 + jg)) * 3;
      else
        pLL = llout + (size_t)zb * ZOUT + (((size_t)b * half + ig) * half + jg) * 3;
      pLL[0] = LLb[0]; pLL[1] = LLb[1]; pLL[2] = LLb[2];
      float* pLH = out + outB + ((size_t)(r0 + ig) * 1024 + (c0 + half + jg)) * 3;
      pLH[0] = LHb[0]; pLH[1] = LHb[1]; pLH[2] = LHb[2];
      float* pHL = out + outB + ((size_t)(r0 + half + ig) * 1024 + (c0 + jg)) * 3;
      pHL[0] = HLb[0]; pHL[1] = HLb[1]; pHL[2] = HLb[2];
      float* pHH = out + outB + ((size_t)(r0 + half + ig) * 1024 + (c0 + half + jg)) * 3;
      pHH[0] = HHb[0]; pHH[1] = HHb[1]; pHH[2] = HHb[2];
    }
  }
}

extern "C" void kernel_launch(void* const* d_in, const int* in_sizes, int n_in,
                              void* d_out, int out_size, void* d_ws, size_t ws_size,
                              hipStream_t stream) {
  (void)in_sizes; (void)n_in; (void)out_size; (void)ws_size;
  const float* x = (const float*)d_in[0];
  float* out = (float*)d_out;
  float* LL1 = (float*)d_ws;        // 4*8*256*256*3 = 6,291,456 floats
  float* LL2 = LL1 + 6291456;       // 4*8*128*128*3 = 1,572,864 floats

  // L0: 512->256. Tile 4x32, LDS 4*220*16 = 14080 B, 4096 blocks.
  fused_level<0, 512, 4, 32, 256><<<dim3(8, 64, 8), 256, 0, stream>>>(x, LL1, out);
  // L1: 256->128. Tile 8x16, LDS 8*244*16 = 31232 B, 1024 blocks.
  fused_level<1, 256, 8, 16, 256><<<dim3(8, 16, 8), 256, 0, stream>>>(LL1, LL2, out);
  // L2: 128->64. Tile 4x16, LDS 4*244*16 = 15616 B, 512 blocks of 128.
  fused_level<2, 128, 4, 16, 128><<<dim3(4, 16, 8), 128, 0, stream>>>(LL2, nullptr, out);
}